// Round 5
// baseline (144.917 us; speedup 1.0000x reference)
//
#include <hip/hip_runtime.h>

#define NB 8
#define NC 512
#define NTOK 1024
#define NHEADS 4
#define DKH 128

typedef unsigned short u16;
typedef __attribute__((ext_vector_type(8))) short bf16x8;   // 8 bf16 (4 VGPRs)
typedef __attribute__((ext_vector_type(4))) float f32x4;

__device__ inline u16 f2b(float f) {
    union { float f; unsigned u; } v; v.f = f;
    unsigned r = v.u + 0x7fffu + ((v.u >> 16) & 1u);   // RNE
    return (u16)(r >> 16);
}

// async global->LDS DMA, 16B per lane; LDS dest = wave-uniform base + lane*16
__device__ __forceinline__ void gll16(const u16* g, u16* l) {
    __builtin_amdgcn_global_load_lds((const __attribute__((address_space(1))) unsigned*)g,
                                     (__attribute__((address_space(3))) unsigned*)l, 16, 0, 0);
}

// ---- fused prep: 3 transpose+convert jobs in one launch ----
__global__ __launch_bounds__(256) void prep(const float* __restrict__ x, const float* __restrict__ Wp,
                                            const float* __restrict__ Wo,
                                            u16* __restrict__ xsb, u16* __restrict__ WpT, u16* __restrict__ WoT)
{
    __shared__ float tile[32][33];
    const int z = blockIdx.z;
    const float* src; u16* dst; int R, Cc;
    if (z == 0)      { src = Wp; dst = WpT; R = 512; Cc = 1536; }
    else if (z == 1) { if (blockIdx.x >= 16) return; src = Wo; dst = WoT; R = 512; Cc = 512; }
    else             { if (blockIdx.x >= 32) return;
                       src = x + (long)(z-2)*NC*NTOK; dst = xsb + (long)(z-2)*NTOK*NC; R = NC; Cc = NTOK; }
    int c0 = blockIdx.x * 32, r0 = blockIdx.y * 32;
    int tx = threadIdx.x, ty = threadIdx.y;
    #pragma unroll
    for (int k = 0; k < 4; ++k)
        tile[ty + 8*k][tx] = src[(long)(r0 + ty + 8*k) * Cc + c0 + tx];
    __syncthreads();
    #pragma unroll
    for (int k = 0; k < 4; ++k)
        dst[(long)(c0 + ty + 8*k) * R + r0 + tx] = f2b(tile[tx][ty + 8*k]);
}

// ---- QKV projection, m97-style DMA staging ----
// q: [b][h][n][d] linear; k: [b][h][n][d] 16B-block XOR swizzled; v: [b][h][d][n] transposed+swizzled
__global__ __launch_bounds__(256) void gemm_qkv(const u16* __restrict__ WpT, const u16* __restrict__ xsb,
                                                const float* __restrict__ bp,
                                                u16* __restrict__ qg, u16* __restrict__ kg, u16* __restrict__ vg)
{
    __shared__ union SmU {
        struct { u16 As[128][64]; u16 Bs[128][64]; } s;   // 32 KB, unpadded (DMA-linear, XOR-swizzled cols)
        u16 Os[4][64][72];                                // 36 KB epilogue overlay
    } sm;
    const int tid = threadIdx.x;
    const int m0 = blockIdx.x * 128;     // qkv column tile
    const int n0 = blockIdx.y * 128;     // token tile
    const int w = tid >> 6, lane = tid & 63, quad = lane >> 4, lc = lane & 15;
    const int mo = (w & 1) * 64, no = (w >> 1) * 64;
    const int sw8 = (((lane & 7) ^ (lane >> 3)) << 3);   // per-lane swizzled 16B-block col offset
    const int xs = lc & 7;

    f32x4 acc[4][4] = {};

    for (int k0 = 0; k0 < NC; k0 += 64) {
        __syncthreads();   // all waves done reading previous tile
        #pragma unroll
        for (int p = 0; p < 4; ++p) {
            int row = w*32 + p*8 + (lane >> 3);
            gll16(&WpT[(long)(m0 + row) * NC + k0 + sw8], &sm.s.As[w*32 + p*8][0]);
            gll16(&xsb[(long)(n0 + row) * NC + k0 + sw8], &sm.s.Bs[w*32 + p*8][0]);
        }
        __syncthreads();   // drains vmcnt(0): tile staged
        #pragma unroll
        for (int ks = 0; ks < 2; ++ks) {
            bf16x8 af[4], bfr[4];
            #pragma unroll
            for (int t = 0; t < 4; ++t) {
                af[t]  = *(const bf16x8*)&sm.s.As[mo + t*16 + lc][((ks*4 + quad) ^ xs) << 3];
                bfr[t] = *(const bf16x8*)&sm.s.Bs[no + t*16 + lc][((ks*4 + quad) ^ xs) << 3];
            }
            #pragma unroll
            for (int mt = 0; mt < 4; ++mt)
                #pragma unroll
                for (int nt = 0; nt < 4; ++nt)
                    acc[mt][nt] = __builtin_amdgcn_mfma_f32_16x16x32_bf16(af[mt], bfr[nt], acc[mt][nt], 0, 0, 0);
        }
    }
    __syncthreads();   // protect Os overlay vs other waves' last-tile reads

    // ---- epilogue ----
    const int bb = n0 >> 10;
    const int nblk = n0 & 1023;
    const int cqb = m0 + mo;
    const int h = cqb / 384;
    const int rem = cqb - h * 384;
    const int sel = rem >> 7;             // 0=q 1=k 2=v (wave-uniform)
    const int d_base = rem & 127;

    #pragma unroll
    for (int mt = 0; mt < 4; ++mt) {
        int cq0 = cqb + mt*16 + quad*4;
        float b0 = bp[cq0+0], b1 = bp[cq0+1], b2 = bp[cq0+2], b3 = bp[cq0+3];
        #pragma unroll
        for (int nt = 0; nt < 4; ++nt) {
            f32x4 a = acc[mt][nt];
            int nl = nt*16 + lc;
            int ml = mt*16 + quad*4;
            u16 e0 = f2b(a[0]+b0), e1 = f2b(a[1]+b1), e2 = f2b(a[2]+b2), e3 = f2b(a[3]+b3);
            if (sel == 2) {
                sm.Os[w][ml+0][nl] = e0; sm.Os[w][ml+1][nl] = e1;
                sm.Os[w][ml+2][nl] = e2; sm.Os[w][ml+3][nl] = e3;
            } else {
                sm.Os[w][nl][ml+0] = e0; sm.Os[w][nl][ml+1] = e1;
                sm.Os[w][nl][ml+2] = e2; sm.Os[w][nl][ml+3] = e3;
            }
        }
    }
    __builtin_amdgcn_sched_barrier(0);   // pin store->load order (wave-local LDS is in-order)

    const long bhbase = (long)(bb * NHEADS + h);
    const int sw = sw8;
    if (sel == 2) {
        #pragma unroll
        for (int pass = 0; pass < 8; ++pass) {
            int ml  = pass*8 + (lane >> 3);
            int nl0 = (lane & 7) * 8;
            bf16x8 vv = *(const bf16x8*)&sm.Os[w][ml][nl0];
            *(bf16x8*)&vg[((bhbase*DKH + d_base + ml) << 10) + nblk + no + sw] = vv;
        }
    } else if (sel == 1) {
        #pragma unroll
        for (int pass = 0; pass < 8; ++pass) {
            int nl  = pass*8 + (lane >> 3);
            int ml0 = (lane & 7) * 8;
            bf16x8 vv = *(const bf16x8*)&sm.Os[w][nl][ml0];
            *(bf16x8*)&kg[((bhbase*NTOK + nblk + no + nl) << 7) + d_base + sw] = vv;
        }
    } else {
        #pragma unroll
        for (int pass = 0; pass < 8; ++pass) {
            int nl  = pass*8 + (lane >> 3);
            int ml0 = (lane & 7) * 8;
            bf16x8 vv = *(const bf16x8*)&sm.Os[w][nl][ml0];
            *(bf16x8*)&qg[((bhbase*NTOK + nblk + no + nl) << 7) + d_base + ml0] = vv;
        }
    }
}

// ---- flash attention v5: 4 waves x 32 q-rows (2 i-blocks), 2x LDS-read reuse ----
// per wave-iter: 36 b128 reads feed 64 MFMAs (was 34 reads / 32 MFMAs)
__global__ __launch_bounds__(256) void attn(const u16* __restrict__ qg, const u16* __restrict__ kg,
                                            const u16* __restrict__ vtg, u16* __restrict__ ho)
{
    __shared__ u16 Ks[2][64*128];   // [j][d'] swizzled, unpadded
    __shared__ u16 Vt[2][128*64];   // [d][j'] swizzled, unpadded
    __shared__ u16 Ps[4][32][72];   // per-wave P[i(32)][j(64)]
    const int tid = threadIdx.x;
    const int w = tid >> 6, lane = tid & 63, quad = lane >> 4, lc = lane & 15;
    // XCD-locality decode: id&7 = XCD residue; 4 (b,h) pairs per residue; 8 i-tiles per pair
    const int id = blockIdx.x;
    const int xcd = id & 7, rest = id >> 3, sub = rest & 3, bx = rest >> 2;
    const int pr = xcd + sub*8;
    const int b = pr >> 2, h = pr & 3;
    const int i0 = bx*128 + w*32;                   // this wave's 32 q-rows
    const long bh = (long)(b * NHEADS + h) << 17;   // *(1024*128)
    const u16* qb = qg + bh;
    const u16* kb = kg + bh;
    const u16* vb = vtg + bh;
    const float SL2E = 0.08838834764831845f * 1.4426950408889634f;  // scale * log2(e)

    bf16x8 qf[2][4];
    #pragma unroll
    for (int ib = 0; ib < 2; ++ib)
        #pragma unroll
        for (int ks = 0; ks < 4; ++ks)
            qf[ib][ks] = *(const bf16x8*)&qb[(long)(i0 + ib*16 + lc) * DKH + ks*32 + quad*8];

    f32x4 o[2][8] = {};
    float lsum[2] = {0.f, 0.f};
    const int xs = lc & 7;

    // stage tile 0 into buffer 0 (4 waves x 4 chunks x 1 KB each for K and V)
    #pragma unroll
    for (int p = 0; p < 4; ++p) {
        int ck = (w*4 + p)*64 + lane;
        gll16(&kb[(long)ck * 8], &Ks[0][(w*4 + p)*512]);
        gll16(&vb[(((long)(ck >> 3)) << 10) + (ck & 7)*8], &Vt[0][(w*4 + p)*512]);
    }

    for (int t = 0; t < 16; ++t) {
        __syncthreads();   // drains vmcnt(0): tile t staged; all waves done with buf[(t-1)&1]
        if (t < 15) {
            long jo = (long)(t+1) * 64;
            #pragma unroll
            for (int p = 0; p < 4; ++p) {
                int ck = (w*4 + p)*64 + lane;
                gll16(&kb[jo*128 + (long)ck*8], &Ks[(t+1)&1][(w*4 + p)*512]);
                gll16(&vb[(((long)(ck >> 3)) << 10) + jo + (ck & 7)*8], &Vt[(t+1)&1][(w*4 + p)*512]);
            }
        }
        const u16* K = Ks[t&1];
        const u16* V = Vt[t&1];

        // S^T = K Q^T: each kf read feeds both i-blocks
        f32x4 s[2][4] = {};
        #pragma unroll
        for (int ks = 0; ks < 4; ++ks)
            #pragma unroll
            for (int jt = 0; jt < 4; ++jt) {
                bf16x8 kf = *(const bf16x8*)&K[(jt*16 + lc)*128 + (((ks*4 + quad) ^ xs) << 3)];
                s[0][jt] = __builtin_amdgcn_mfma_f32_16x16x32_bf16(kf, qf[0][ks], s[0][jt], 0, 0, 0);
                s[1][jt] = __builtin_amdgcn_mfma_f32_16x16x32_bf16(kf, qf[1][ks], s[1][jt], 0, 0, 0);
            }

        // softmax, no max subtraction (bounded logits), lane-local row sums
        #pragma unroll
        for (int ib = 0; ib < 2; ++ib)
            #pragma unroll
            for (int jt = 0; jt < 4; ++jt) {
                float p0 = __builtin_amdgcn_exp2f(s[ib][jt][0] * SL2E);
                float p1 = __builtin_amdgcn_exp2f(s[ib][jt][1] * SL2E);
                float p2 = __builtin_amdgcn_exp2f(s[ib][jt][2] * SL2E);
                float p3 = __builtin_amdgcn_exp2f(s[ib][jt][3] * SL2E);
                lsum[ib] += (p0 + p1) + (p2 + p3);
                ushort4 pk;
                pk.x = f2b(p0); pk.y = f2b(p1); pk.z = f2b(p2); pk.w = f2b(p3);
                *(ushort4*)&Ps[w][ib*16 + lc][jt*16 + quad*4] = pk;   // P[i][j-run]
            }
        __builtin_amdgcn_sched_barrier(0);  // wave-private Ps: pin write->read order

        // O^T += V^T P^T: each vf read feeds both i-blocks
        #pragma unroll
        for (int ks2 = 0; ks2 < 2; ++ks2) {
            bf16x8 pf0 = *(const bf16x8*)&Ps[w][lc][ks2*32 + quad*8];
            bf16x8 pf1 = *(const bf16x8*)&Ps[w][16 + lc][ks2*32 + quad*8];
            #pragma unroll
            for (int dt = 0; dt < 8; ++dt) {
                bf16x8 vf = *(const bf16x8*)&V[(dt*16 + lc)*64 + (((ks2*4 + quad) ^ xs) << 3)];
                o[0][dt] = __builtin_amdgcn_mfma_f32_16x16x32_bf16(vf, pf0, o[0][dt], 0, 0, 0);
                o[1][dt] = __builtin_amdgcn_mfma_f32_16x16x32_bf16(vf, pf1, o[1][dt], 0, 0, 0);
            }
        }
    }

    #pragma unroll
    for (int ib = 0; ib < 2; ++ib) {
        float l = lsum[ib];
        l += __shfl_xor(l, 16);
        l += __shfl_xor(l, 32);
        float inv = 1.0f / l;
        #pragma unroll
        for (int dt = 0; dt < 8; ++dt) {
            ushort4 pk;
            pk.x = f2b(o[ib][dt][0] * inv); pk.y = f2b(o[ib][dt][1] * inv);
            pk.z = f2b(o[ib][dt][2] * inv); pk.w = f2b(o[ib][dt][3] * inv);
            *(ushort4*)&ho[(long)(b*NTOK + i0 + ib*16 + lc) * NC + h*DKH + dt*16 + quad*4] = pk;
        }
    }
}

// ---- output projection + bias + fp32 residual, 128m x 64n tiles, DMA staging ----
__global__ __launch_bounds__(256) void gemm_out(const u16* __restrict__ WoT, const u16* __restrict__ ho,
                                                const float* __restrict__ bo, const float* __restrict__ xin,
                                                float* __restrict__ dout)
{
    __shared__ struct { u16 As[128][64]; u16 Bs[64][64]; } sm;   // 24 KB
    const int tid = threadIdx.x;
    const int m0 = blockIdx.x * 128;     // out-channel tile
    const int n0 = blockIdx.y * 64;      // token tile
    const int w = tid >> 6, lane = tid & 63, quad = lane >> 4, lc = lane & 15;
    const int mo = (w & 1) * 64, no = (w >> 1) * 32;
    const int sw8 = (((lane & 7) ^ (lane >> 3)) << 3);
    const int xs = lc & 7;

    f32x4 acc[4][2] = {};

    for (int k0 = 0; k0 < NC; k0 += 64) {
        __syncthreads();
        #pragma unroll
        for (int p = 0; p < 4; ++p) {
            int row = w*32 + p*8 + (lane >> 3);
            gll16(&WoT[(long)(m0 + row) * NC + k0 + sw8], &sm.As[w*32 + p*8][0]);
        }
        #pragma unroll
        for (int p = 0; p < 2; ++p) {
            int row = w*16 + p*8 + (lane >> 3);
            gll16(&ho[(long)(n0 + row) * NC + k0 + sw8], &sm.Bs[w*16 + p*8][0]);
        }
        __syncthreads();
        #pragma unroll
        for (int ks = 0; ks < 2; ++ks) {
            bf16x8 af[4], bfr[2];
            #pragma unroll
            for (int t = 0; t < 4; ++t)
                af[t] = *(const bf16x8*)&sm.As[mo + t*16 + lc][((ks*4 + quad) ^ xs) << 3];
            #pragma unroll
            for (int t = 0; t < 2; ++t)
                bfr[t] = *(const bf16x8*)&sm.Bs[no + t*16 + lc][((ks*4 + quad) ^ xs) << 3];
            #pragma unroll
            for (int mt = 0; mt < 4; ++mt)
                #pragma unroll
                for (int nt = 0; nt < 2; ++nt)
                    acc[mt][nt] = __builtin_amdgcn_mfma_f32_16x16x32_bf16(af[mt], bfr[nt], acc[mt][nt], 0, 0, 0);
        }
    }

    const int bb = n0 >> 10;
    #pragma unroll
    for (int mt = 0; mt < 4; ++mt) {
        int cc0 = m0 + mo + mt*16 + quad*4;
        float b0 = bo[cc0+0], b1 = bo[cc0+1], b2 = bo[cc0+2], b3 = bo[cc0+3];
        #pragma unroll
        for (int nt = 0; nt < 2; ++nt) {
            int nl = (n0 + no + nt*16 + lc) & (NTOK - 1);
            f32x4 a = acc[mt][nt];
            long ix = ((long)(bb*NC + cc0) << 10) + nl;
            dout[ix]             = a[0] + b0 + xin[ix];
            dout[ix + (1 << 10)] = a[1] + b1 + xin[ix + (1 << 10)];
            dout[ix + (2 << 10)] = a[2] + b2 + xin[ix + (2 << 10)];
            dout[ix + (3 << 10)] = a[3] + b3 + xin[ix + (3 << 10)];
        }
    }
}

extern "C" void kernel_launch(void* const* d_in, const int* in_sizes, int n_in,
                              void* d_out, int out_size, void* d_ws, size_t ws_size,
                              hipStream_t stream)
{
    (void)in_sizes; (void)n_in; (void)out_size; (void)ws_size;
    const float* x  = (const float*)d_in[0];
    const float* Wp = (const float*)d_in[1];
    const float* bp = (const float*)d_in[2];
    const float* Wo = (const float*)d_in[3];
    const float* bo = (const float*)d_in[4];
    float* out = (float*)d_out;

    // workspace layout (u16 elements), total ~42 MiB
    u16* ws  = (u16*)d_ws;
    u16* xsb = ws;                                   // [8192][512] bf16
    u16* WpT = xsb + (long)NB * NTOK * NC;           // [1536][512]
    u16* WoT = WpT + 1536L * 512;                    // [512][512]
    u16* qg  = WoT + 512L * 512;                     // [8][4][1024][128]
    u16* kg  = qg + (long)NB * NHEADS * NTOK * DKH;  // [8][4][1024][128]  (swizzled)
    u16* vtg = kg + (long)NB * NHEADS * NTOK * DKH;  // [8][4][128][1024]  (V transposed, swizzled)
    u16* ho  = vtg + (long)NB * NHEADS * NTOK * DKH; // [8192][512]

    prep<<<dim3(48, 16, 10), dim3(32, 8), 0, stream>>>(x, Wp, Wo, xsb, WpT, WoT);
    gemm_qkv<<<dim3(1536/128, (NB*NTOK)/128), 256, 0, stream>>>(WpT, xsb, bp, qg, kg, vtg);
    attn<<<dim3(256), 256, 0, stream>>>(qg, kg, vtg, ho);
    gemm_out<<<dim3(NC/128, (NB*NTOK)/64), 256, 0, stream>>>(WoT, ho, bo, x, out);
}

// Round 6
// 142.381 us; speedup vs baseline: 1.0178x; 1.0178x over previous
//
#include <hip/hip_runtime.h>

#define NB 8
#define NC 512
#define NTOK 1024
#define NHEADS 4
#define DKH 128

typedef unsigned short u16;
typedef __attribute__((ext_vector_type(8))) short bf16x8;   // 8 bf16 (4 VGPRs)
typedef __attribute__((ext_vector_type(4))) float f32x4;

__device__ inline u16 f2b(float f) {
    union { float f; unsigned u; } v; v.f = f;
    unsigned r = v.u + 0x7fffu + ((v.u >> 16) & 1u);   // RNE
    return (u16)(r >> 16);
}

// async global->LDS DMA, 16B per lane; LDS dest = wave-uniform base + lane*16
__device__ __forceinline__ void gll16(const u16* g, u16* l) {
    __builtin_amdgcn_global_load_lds((const __attribute__((address_space(1))) unsigned*)g,
                                     (__attribute__((address_space(3))) unsigned*)l, 16, 0, 0);
}

// ---- fused prep: 3 transpose+convert jobs in one launch ----
__global__ __launch_bounds__(256) void prep(const float* __restrict__ x, const float* __restrict__ Wp,
                                            const float* __restrict__ Wo,
                                            u16* __restrict__ xsb, u16* __restrict__ WpT, u16* __restrict__ WoT)
{
    __shared__ float tile[32][33];
    const int z = blockIdx.z;
    const float* src; u16* dst; int R, Cc;
    if (z == 0)      { src = Wp; dst = WpT; R = 512; Cc = 1536; }
    else if (z == 1) { if (blockIdx.x >= 16) return; src = Wo; dst = WoT; R = 512; Cc = 512; }
    else             { if (blockIdx.x >= 32) return;
                       src = x + (long)(z-2)*NC*NTOK; dst = xsb + (long)(z-2)*NTOK*NC; R = NC; Cc = NTOK; }
    int c0 = blockIdx.x * 32, r0 = blockIdx.y * 32;
    int tx = threadIdx.x, ty = threadIdx.y;
    #pragma unroll
    for (int k = 0; k < 4; ++k)
        tile[ty + 8*k][tx] = src[(long)(r0 + ty + 8*k) * Cc + c0 + tx];
    __syncthreads();
    #pragma unroll
    for (int k = 0; k < 4; ++k)
        dst[(long)(c0 + ty + 8*k) * R + r0 + tx] = f2b(tile[tx][ty + 8*k]);
}

// ---- QKV projection, m97-style DMA staging ----
// q: [b][h][n][d] linear; k: [b][h][n][d] 16B-block XOR swizzled; v: [b][h][d][n] transposed+swizzled
__global__ __launch_bounds__(256) void gemm_qkv(const u16* __restrict__ WpT, const u16* __restrict__ xsb,
                                                const float* __restrict__ bp,
                                                u16* __restrict__ qg, u16* __restrict__ kg, u16* __restrict__ vg)
{
    __shared__ union SmU {
        struct { u16 As[128][64]; u16 Bs[128][64]; } s;   // 32 KB, unpadded (DMA-linear, XOR-swizzled cols)
        u16 Os[4][64][72];                                // 36 KB epilogue overlay
    } sm;
    const int tid = threadIdx.x;
    const int m0 = blockIdx.x * 128;     // qkv column tile
    const int n0 = blockIdx.y * 128;     // token tile
    const int w = tid >> 6, lane = tid & 63, quad = lane >> 4, lc = lane & 15;
    const int mo = (w & 1) * 64, no = (w >> 1) * 64;
    const int sw8 = (((lane & 7) ^ (lane >> 3)) << 3);   // per-lane swizzled 16B-block col offset
    const int xs = lc & 7;

    f32x4 acc[4][4] = {};

    for (int k0 = 0; k0 < NC; k0 += 64) {
        __syncthreads();   // all waves done reading previous tile
        #pragma unroll
        for (int p = 0; p < 4; ++p) {
            int row = w*32 + p*8 + (lane >> 3);
            gll16(&WpT[(long)(m0 + row) * NC + k0 + sw8], &sm.s.As[w*32 + p*8][0]);
            gll16(&xsb[(long)(n0 + row) * NC + k0 + sw8], &sm.s.Bs[w*32 + p*8][0]);
        }
        __syncthreads();   // drains vmcnt(0): tile staged
        #pragma unroll
        for (int ks = 0; ks < 2; ++ks) {
            bf16x8 af[4], bfr[4];
            #pragma unroll
            for (int t = 0; t < 4; ++t) {
                af[t]  = *(const bf16x8*)&sm.s.As[mo + t*16 + lc][((ks*4 + quad) ^ xs) << 3];
                bfr[t] = *(const bf16x8*)&sm.s.Bs[no + t*16 + lc][((ks*4 + quad) ^ xs) << 3];
            }
            #pragma unroll
            for (int mt = 0; mt < 4; ++mt)
                #pragma unroll
                for (int nt = 0; nt < 4; ++nt)
                    acc[mt][nt] = __builtin_amdgcn_mfma_f32_16x16x32_bf16(af[mt], bfr[nt], acc[mt][nt], 0, 0, 0);
        }
    }
    __syncthreads();   // protect Os overlay vs other waves' last-tile reads

    // ---- epilogue ----
    const int bb = n0 >> 10;
    const int nblk = n0 & 1023;
    const int cqb = m0 + mo;
    const int h = cqb / 384;
    const int rem = cqb - h * 384;
    const int sel = rem >> 7;             // 0=q 1=k 2=v (wave-uniform)
    const int d_base = rem & 127;

    #pragma unroll
    for (int mt = 0; mt < 4; ++mt) {
        int cq0 = cqb + mt*16 + quad*4;
        float b0 = bp[cq0+0], b1 = bp[cq0+1], b2 = bp[cq0+2], b3 = bp[cq0+3];
        #pragma unroll
        for (int nt = 0; nt < 4; ++nt) {
            f32x4 a = acc[mt][nt];
            int nl = nt*16 + lc;
            int ml = mt*16 + quad*4;
            u16 e0 = f2b(a[0]+b0), e1 = f2b(a[1]+b1), e2 = f2b(a[2]+b2), e3 = f2b(a[3]+b3);
            if (sel == 2) {
                sm.Os[w][ml+0][nl] = e0; sm.Os[w][ml+1][nl] = e1;
                sm.Os[w][ml+2][nl] = e2; sm.Os[w][ml+3][nl] = e3;
            } else {
                sm.Os[w][nl][ml+0] = e0; sm.Os[w][nl][ml+1] = e1;
                sm.Os[w][nl][ml+2] = e2; sm.Os[w][nl][ml+3] = e3;
            }
        }
    }
    __builtin_amdgcn_sched_barrier(0);   // pin store->load order (wave-local LDS is in-order)

    const long bhbase = (long)(bb * NHEADS + h);
    const int sw = sw8;
    if (sel == 2) {
        #pragma unroll
        for (int pass = 0; pass < 8; ++pass) {
            int ml  = pass*8 + (lane >> 3);
            int nl0 = (lane & 7) * 8;
            bf16x8 vv = *(const bf16x8*)&sm.Os[w][ml][nl0];
            *(bf16x8*)&vg[((bhbase*DKH + d_base + ml) << 10) + nblk + no + sw] = vv;
        }
    } else if (sel == 1) {
        #pragma unroll
        for (int pass = 0; pass < 8; ++pass) {
            int nl  = pass*8 + (lane >> 3);
            int ml0 = (lane & 7) * 8;
            bf16x8 vv = *(const bf16x8*)&sm.Os[w][nl][ml0];
            *(bf16x8*)&kg[((bhbase*NTOK + nblk + no + nl) << 7) + d_base + sw] = vv;
        }
    } else {
        #pragma unroll
        for (int pass = 0; pass < 8; ++pass) {
            int nl  = pass*8 + (lane >> 3);
            int ml0 = (lane & 7) * 8;
            bf16x8 vv = *(const bf16x8*)&sm.Os[w][nl][ml0];
            *(bf16x8*)&qg[((bhbase*NTOK + nblk + no + nl) << 7) + d_base + ml0] = vv;
        }
    }
}

// ---- flash attention v6: 8 waves = 4 i-waves x 2 j-halves; 32 i-rows x 32 j-cols per wave ----
// 2x A-operand LDS reuse at 2 waves/SIMD occupancy (v4 topology + v5 reuse)
// per wave-iter: 8 kf + 8 vf + 2 pf b128 reads + 4 b64 P-stores feed 32 MFMAs
__global__ __launch_bounds__(512, 2) void attn(const u16* __restrict__ qg, const u16* __restrict__ kg,
                                               const u16* __restrict__ vtg, u16* __restrict__ ho)
{
    __shared__ union {
        struct { u16 Ks[2][64*128]; u16 Vt[2][128*64]; } kv;     // 64 KB staging
        struct { float Om[4][32][132]; float Ls[4][32]; } mg;    // 68 KB j-merge overlay (dead kv)
    } sm;
    __shared__ u16 Ps[8][32][40];   // per-wave P[i(32)][j(32)], pad 8
    const int tid = threadIdx.x;
    const int w = tid >> 6, lane = tid & 63, quad = lane >> 4, lc = lane & 15;
    const int iw = w & 3, jh = w >> 2;              // i-wave, j-half
    // XCD-locality decode: id&7 = XCD residue; 4 (b,h) pairs per residue; 8 i-tiles per pair
    const int id = blockIdx.x;
    const int xcd = id & 7, rest = id >> 3, sub = rest & 3, bx = rest >> 2;
    const int pr = xcd + sub*8;
    const int b = pr >> 2, h = pr & 3;
    const int i0 = bx*128 + iw*32;                  // this wave's 32 q-rows
    const long bh = (long)(b * NHEADS + h) << 17;   // *(1024*128)
    const u16* qb = qg + bh;
    const u16* kb = kg + bh;
    const u16* vb = vtg + bh;
    const float SL2E = 0.08838834764831845f * 1.4426950408889634f;  // scale * log2(e)

    bf16x8 qf[2][4];
    #pragma unroll
    for (int ib = 0; ib < 2; ++ib)
        #pragma unroll
        for (int ks = 0; ks < 4; ++ks)
            qf[ib][ks] = *(const bf16x8*)&qb[(long)(i0 + ib*16 + lc) * DKH + ks*32 + quad*8];

    f32x4 o[2][8] = {};
    float lsum[2] = {0.f, 0.f};
    const int xs = lc & 7;

    // stage tile 0 into buffer 0 (8 waves x 2 chunks x 1 KB each for K and V)
    #pragma unroll
    for (int p = 0; p < 2; ++p) {
        int ck = (w*2 + p)*64 + lane;
        gll16(&kb[(long)ck * 8], &sm.kv.Ks[0][(w*2 + p)*512]);
        gll16(&vb[(((long)(ck >> 3)) << 10) + (ck & 7)*8], &sm.kv.Vt[0][(w*2 + p)*512]);
    }

    for (int t = 0; t < 16; ++t) {
        __syncthreads();   // drains vmcnt(0): tile t staged; all waves done with buf[(t-1)&1]
        if (t < 15) {
            long jo = (long)(t+1) * 64;
            #pragma unroll
            for (int p = 0; p < 2; ++p) {
                int ck = (w*2 + p)*64 + lane;
                gll16(&kb[jo*128 + (long)ck*8], &sm.kv.Ks[(t+1)&1][(w*2 + p)*512]);
                gll16(&vb[(((long)(ck >> 3)) << 10) + jo + (ck & 7)*8], &sm.kv.Vt[(t+1)&1][(w*2 + p)*512]);
            }
        }
        const u16* K = sm.kv.Ks[t&1];
        const u16* V = sm.kv.Vt[t&1];

        // S^T = K Q^T on this wave's 32-j half: each kf read feeds both i-blocks
        f32x4 s[2][2] = {};
        #pragma unroll
        for (int ks = 0; ks < 4; ++ks)
            #pragma unroll
            for (int jt = 0; jt < 2; ++jt) {
                bf16x8 kf = *(const bf16x8*)&K[(jh*32 + jt*16 + lc)*128 + (((ks*4 + quad) ^ xs) << 3)];
                s[0][jt] = __builtin_amdgcn_mfma_f32_16x16x32_bf16(kf, qf[0][ks], s[0][jt], 0, 0, 0);
                s[1][jt] = __builtin_amdgcn_mfma_f32_16x16x32_bf16(kf, qf[1][ks], s[1][jt], 0, 0, 0);
            }

        // softmax, no max subtraction (bounded logits), lane-local partial row sums
        #pragma unroll
        for (int ib = 0; ib < 2; ++ib)
            #pragma unroll
            for (int jt = 0; jt < 2; ++jt) {
                float p0 = __builtin_amdgcn_exp2f(s[ib][jt][0] * SL2E);
                float p1 = __builtin_amdgcn_exp2f(s[ib][jt][1] * SL2E);
                float p2 = __builtin_amdgcn_exp2f(s[ib][jt][2] * SL2E);
                float p3 = __builtin_amdgcn_exp2f(s[ib][jt][3] * SL2E);
                lsum[ib] += (p0 + p1) + (p2 + p3);
                ushort4 pk;
                pk.x = f2b(p0); pk.y = f2b(p1); pk.z = f2b(p2); pk.w = f2b(p3);
                *(ushort4*)&Ps[w][ib*16 + lc][jt*16 + quad*4] = pk;   // P[i][j-local run]
            }
        __builtin_amdgcn_sched_barrier(0);  // wave-private Ps: pin write->read order

        // O^T += V^T P^T over this wave's 32 j (K=32 MFMA): each vf read feeds both i-blocks
        {
            bf16x8 pf0 = *(const bf16x8*)&Ps[w][lc][quad*8];
            bf16x8 pf1 = *(const bf16x8*)&Ps[w][16 + lc][quad*8];
            #pragma unroll
            for (int dt = 0; dt < 8; ++dt) {
                bf16x8 vf = *(const bf16x8*)&V[(dt*16 + lc)*64 + (((jh*4 + quad) ^ xs) << 3)];
                o[0][dt] = __builtin_amdgcn_mfma_f32_16x16x32_bf16(vf, pf0, o[0][dt], 0, 0, 0);
                o[1][dt] = __builtin_amdgcn_mfma_f32_16x16x32_bf16(vf, pf1, o[1][dt], 0, 0, 0);
            }
        }
    }

    // quad-reduce partial row sums (lanes sharing i = lc)
    #pragma unroll
    for (int ib = 0; ib < 2; ++ib) {
        lsum[ib] += __shfl_xor(lsum[ib], 16);
        lsum[ib] += __shfl_xor(lsum[ib], 32);
    }

    // merge the two j-halves through LDS (kv buffers are dead now)
    __syncthreads();
    if (jh == 1) {
        #pragma unroll
        for (int ib = 0; ib < 2; ++ib)
            #pragma unroll
            for (int dt = 0; dt < 8; ++dt)
                *(f32x4*)&sm.mg.Om[iw][ib*16 + lc][dt*16 + quad*4] = o[ib][dt];
        if (quad == 0) { sm.mg.Ls[iw][lc] = lsum[0]; sm.mg.Ls[iw][16 + lc] = lsum[1]; }
    }
    __syncthreads();
    if (jh == 0) {
        #pragma unroll
        for (int ib = 0; ib < 2; ++ib) {
            float inv = 1.0f / (lsum[ib] + sm.mg.Ls[iw][ib*16 + lc]);
            #pragma unroll
            for (int dt = 0; dt < 8; ++dt) {
                f32x4 oo = o[ib][dt] + *(const f32x4*)&sm.mg.Om[iw][ib*16 + lc][dt*16 + quad*4];
                ushort4 pk;
                pk.x = f2b(oo[0] * inv); pk.y = f2b(oo[1] * inv);
                pk.z = f2b(oo[2] * inv); pk.w = f2b(oo[3] * inv);
                *(ushort4*)&ho[(long)(b*NTOK + i0 + ib*16 + lc) * NC + h*DKH + dt*16 + quad*4] = pk;
            }
        }
    }
}

// ---- output projection + bias + fp32 residual, 128m x 64n tiles, DMA staging ----
__global__ __launch_bounds__(256) void gemm_out(const u16* __restrict__ WoT, const u16* __restrict__ ho,
                                                const float* __restrict__ bo, const float* __restrict__ xin,
                                                float* __restrict__ dout)
{
    __shared__ struct { u16 As[128][64]; u16 Bs[64][64]; } sm;   // 24 KB
    const int tid = threadIdx.x;
    const int m0 = blockIdx.x * 128;     // out-channel tile
    const int n0 = blockIdx.y * 64;      // token tile
    const int w = tid >> 6, lane = tid & 63, quad = lane >> 4, lc = lane & 15;
    const int mo = (w & 1) * 64, no = (w >> 1) * 32;
    const int sw8 = (((lane & 7) ^ (lane >> 3)) << 3);
    const int xs = lc & 7;

    f32x4 acc[4][2] = {};

    for (int k0 = 0; k0 < NC; k0 += 64) {
        __syncthreads();
        #pragma unroll
        for (int p = 0; p < 4; ++p) {
            int row = w*32 + p*8 + (lane >> 3);
            gll16(&WoT[(long)(m0 + row) * NC + k0 + sw8], &sm.As[w*32 + p*8][0]);
        }
        #pragma unroll
        for (int p = 0; p < 2; ++p) {
            int row = w*16 + p*8 + (lane >> 3);
            gll16(&ho[(long)(n0 + row) * NC + k0 + sw8], &sm.Bs[w*16 + p*8][0]);
        }
        __syncthreads();
        #pragma unroll
        for (int ks = 0; ks < 2; ++ks) {
            bf16x8 af[4], bfr[2];
            #pragma unroll
            for (int t = 0; t < 4; ++t)
                af[t] = *(const bf16x8*)&sm.As[mo + t*16 + lc][((ks*4 + quad) ^ xs) << 3];
            #pragma unroll
            for (int t = 0; t < 2; ++t)
                bfr[t] = *(const bf16x8*)&sm.Bs[no + t*16 + lc][((ks*4 + quad) ^ xs) << 3];
            #pragma unroll
            for (int mt = 0; mt < 4; ++mt)
                #pragma unroll
                for (int nt = 0; nt < 2; ++nt)
                    acc[mt][nt] = __builtin_amdgcn_mfma_f32_16x16x32_bf16(af[mt], bfr[nt], acc[mt][nt], 0, 0, 0);
        }
    }

    const int bb = n0 >> 10;
    #pragma unroll
    for (int mt = 0; mt < 4; ++mt) {
        int cc0 = m0 + mo + mt*16 + quad*4;
        float b0 = bo[cc0+0], b1 = bo[cc0+1], b2 = bo[cc0+2], b3 = bo[cc0+3];
        #pragma unroll
        for (int nt = 0; nt < 2; ++nt) {
            int nl = (n0 + no + nt*16 + lc) & (NTOK - 1);
            f32x4 a = acc[mt][nt];
            long ix = ((long)(bb*NC + cc0) << 10) + nl;
            dout[ix]             = a[0] + b0 + xin[ix];
            dout[ix + (1 << 10)] = a[1] + b1 + xin[ix + (1 << 10)];
            dout[ix + (2 << 10)] = a[2] + b2 + xin[ix + (2 << 10)];
            dout[ix + (3 << 10)] = a[3] + b3 + xin[ix + (3 << 10)];
        }
    }
}

extern "C" void kernel_launch(void* const* d_in, const int* in_sizes, int n_in,
                              void* d_out, int out_size, void* d_ws, size_t ws_size,
                              hipStream_t stream)
{
    (void)in_sizes; (void)n_in; (void)out_size; (void)ws_size;
    const float* x  = (const float*)d_in[0];
    const float* Wp = (const float*)d_in[1];
    const float* bp = (const float*)d_in[2];
    const float* Wo = (const float*)d_in[3];
    const float* bo = (const float*)d_in[4];
    float* out = (float*)d_out;

    // workspace layout (u16 elements), total ~42 MiB
    u16* ws  = (u16*)d_ws;
    u16* xsb = ws;                                   // [8192][512] bf16
    u16* WpT = xsb + (long)NB * NTOK * NC;           // [1536][512]
    u16* WoT = WpT + 1536L * 512;                    // [512][512]
    u16* qg  = WoT + 512L * 512;                     // [8][4][1024][128]
    u16* kg  = qg + (long)NB * NHEADS * NTOK * DKH;  // [8][4][1024][128]  (swizzled)
    u16* vtg = kg + (long)NB * NHEADS * NTOK * DKH;  // [8][4][128][1024]  (V transposed, swizzled)
    u16* ho  = vtg + (long)NB * NHEADS * NTOK * DKH; // [8192][512]

    prep<<<dim3(48, 16, 10), dim3(32, 8), 0, stream>>>(x, Wp, Wo, xsb, WpT, WoT);
    gemm_qkv<<<dim3(1536/128, (NB*NTOK)/128), 256, 0, stream>>>(WpT, xsb, bp, qg, kg, vtg);
    attn<<<dim3(256), 512, 0, stream>>>(qg, kg, vtg, ho);
    gemm_out<<<dim3(NC/128, (NB*NTOK)/64), 256, 0, stream>>>(WoT, ho, bo, x, out);
}